// Round 9
// baseline (559.365 us; speedup 1.0000x reference)
//
#include <hip/hip_runtime.h>
#include <hip/hip_bf16.h>

static constexpr int N_NODES = 100000;
static constexpr int N_EDGES = 3200000;
static constexpr int IN_CH = 512;
static constexpr int H = 16;
static constexpr int TB = 256;

static constexpr int BN = 256;                       // nodes per bucket
static constexpr int NB = (N_NODES + BN - 1) / BN;   // 391 buckets
static constexpr int CAP = 8960;                     // ebuf slots/bucket (mean 8192, +8.5 sigma)
static constexpr int CAP2 = CAP + 3 * BN;            // 9728: sorted+padded slots (mult of 4)
static constexpr int CHUNK = 8192;                   // edges per scatter WG
static constexpr int GRID_SC = (N_EDGES + CHUNK - 1) / CHUNK;  // 391
static constexpr int NBLK64 = (N_NODES + 63) / 64;   // 1563 (gather grids)

// gcur[b] = b*CAP  (bump cursors into fixed-capacity bucket regions)
__global__ void k_init(int* __restrict__ gcur) {
  int b = blockIdx.x * blockDim.x + threadIdx.x;
  if (b < NB) gcur[b] = b * CAP;
}

// Chunked reserve-then-write scatter (one contiguous run per (WG,bucket)).
// pack = (dst&255)<<17 | src  (src < 2^17)
__global__ void k_cscatter(const int* __restrict__ ei, int* __restrict__ gcur,
                           int* __restrict__ ebuf) {
  __shared__ int cnt[NB];
  __shared__ int gofs[NB];
  int t = threadIdx.x;
  int c0 = blockIdx.x * CHUNK;
  int c1 = min(c0 + CHUNK, N_EDGES);
  for (int b = t; b < NB; b += TB) cnt[b] = 0;
  __syncthreads();
  for (int j = c0 + t; j < c1; j += TB) atomicAdd(&cnt[ei[N_EDGES + j] >> 8], 1);
  __syncthreads();
  for (int b = t; b < NB; b += TB)
    if (cnt[b] > 0) gofs[b] = atomicAdd(&gcur[b], cnt[b]);
  __syncthreads();
  for (int j = c0 + t; j < c1; j += TB) {
    int s = ei[j];
    int d = ei[N_EDGES + j];
    int slot = atomicAdd(&gofs[d >> 8], 1);
    ebuf[slot] = ((d & 255) << 17) | s;
  }
}

// Per-bucket counting sort with 4-slot-aligned per-node runs; pads point at
// dummy node N_NODES (hs[N]=0). Emits nrs/nend (padded end) and disq.
__global__ void k_bsort(const int* __restrict__ gcur, const int* __restrict__ ebuf,
                        int* __restrict__ ebuf2, int* __restrict__ nrs,
                        int* __restrict__ nend, float* __restrict__ disq) {
  __shared__ int cnt[BN];
  __shared__ int pre[BN];
  __shared__ int cur[BN];
  int b = blockIdx.x, t = threadIdx.x;
  cnt[t] = 0;
  __syncthreads();
  int beg = b * CAP, end = gcur[b];
  for (int j = beg + t; j < end; j += TB) atomicAdd(&cnt[ebuf[j] >> 17], 1);
  __syncthreads();
  int myc = cnt[t];
  int ac = (myc + 3) & ~3;
  pre[t] = ac;
  __syncthreads();
  for (int off = 1; off < TB; off <<= 1) {
    int v = (t >= off) ? pre[t - off] : 0;
    __syncthreads();
    pre[t] += v;
    __syncthreads();
  }
  int start = b * CAP2 + ((t == 0) ? 0 : pre[t - 1]);
  cur[t] = start;
  int node = b * BN + t;
  if (node < N_NODES) {
    nrs[node] = start;
    nend[node] = start + ac;
    disq[node] = 1.0f / sqrtf((float)myc + 1.0f);
    for (int j = start + myc; j < start + ac; j++) ebuf2[j] = N_NODES;  // dummy pads
  }
  __syncthreads();
  for (int j = beg + t; j < end; j += TB) {
    int p = ebuf[j];
    int slot = atomicAdd(&cur[p >> 17], 1);
    ebuf2[slot] = p & 0x1FFFF;
  }
}

// hsA = (X @ W1) * disq[row], single [N+1][16] table; dummy row N zeroed in
// hsA, hsB, hs3. TB=64 for CU balance (1564 WGs).
__global__ void k_gemm1(const float* __restrict__ x, const float* __restrict__ W,
                        const float* __restrict__ disq,
                        float* __restrict__ hsA, float* __restrict__ hsB,
                        float* __restrict__ hs3) {
  int r = blockIdx.x * blockDim.x + threadIdx.x;
  if (r > N_NODES) return;
  if (r == N_NODES) {  // dummy rows for gather pads
    float4 z = make_float4(0.f, 0.f, 0.f, 0.f);
#pragma unroll
    for (int q = 0; q < 4; q++) {
      ((float4*)(hsA + (size_t)r * H))[q] = z;
      ((float4*)(hsB + (size_t)r * H))[q] = z;
    }
    hs3[r] = 0.f;
    return;
  }
  const float4* xr = (const float4*)(x + (size_t)r * IN_CH);
  float acc[H];
#pragma unroll
  for (int c = 0; c < H; c++) acc[c] = 0.f;
  for (int k4 = 0; k4 < IN_CH / 4; k4++) {
    float4 xv = xr[k4];
    const float* wr = W + k4 * 4 * H;
    float xs[4] = {xv.x, xv.y, xv.z, xv.w};
#pragma unroll
    for (int j = 0; j < 4; j++) {
#pragma unroll
      for (int c = 0; c < H; c++) acc[c] = fmaf(xs[j], wr[j * H + c], acc[c]);
    }
  }
  float dn = disq[r];
  float4* o = (float4*)(hsA + (size_t)r * H);
#pragma unroll
  for (int q = 0; q < 4; q++)
    o[q] = make_float4(acc[4 * q + 0] * dn, acc[4 * q + 1] * dn,
                       acc[4 * q + 2] * dn, acc[4 * q + 3] * dn);
}

// Fused gather (float4/lane, 4 edges/iter) + relu + 16x16 GEMM + disq scale.
// 4 lanes per node (lane = channel quad), 64 nodes per WG.
__global__ void k_gath_mid(const int* __restrict__ nrs, const int* __restrict__ nend,
                           const int* __restrict__ ebuf2, const float* __restrict__ disq,
                           const float* __restrict__ hs, const float* __restrict__ W2,
                           const float* __restrict__ bias, float* __restrict__ ouths) {
  __shared__ float agg[64 * 16];
  __shared__ float w[256];
  int b = blockIdx.x, t = threadIdx.x;
  w[t] = W2[t];
  int grp = t >> 2, lane = t & 3;  // 64 groups (nodes) x 4 lanes
  int node = b * 64 + grp;
  const float4* hs4 = (const float4*)hs;
  if (node < N_NODES) {
    int beg = nrs[node], endp = nend[node];
    float4 a = make_float4(0.f, 0.f, 0.f, 0.f);
    for (int j = beg; j < endp; j += 4) {
      int4 s = *(const int4*)(ebuf2 + j);
      float4 v0 = hs4[s.x * 4 + lane];
      float4 v1 = hs4[s.y * 4 + lane];
      float4 v2 = hs4[s.z * 4 + lane];
      float4 v3 = hs4[s.w * 4 + lane];
      a.x += (v0.x + v1.x) + (v2.x + v3.x);
      a.y += (v0.y + v1.y) + (v2.y + v3.y);
      a.z += (v0.z + v1.z) + (v2.z + v3.z);
      a.w += (v0.w + v1.w) + (v2.w + v3.w);
    }
    float dn = disq[node];
    float4 self = hs4[node * 4 + lane];
    float4 bv = *(const float4*)(bias + lane * 4);
    float4 r;
    r.x = fmaf(a.x + self.x, dn, bv.x);
    r.y = fmaf(a.y + self.y, dn, bv.y);
    r.z = fmaf(a.z + self.z, dn, bv.z);
    r.w = fmaf(a.w + self.w, dn, bv.w);
    *(float4*)(agg + grp * 16 + lane * 4) = r;
  }
  __syncthreads();
  int nl = t >> 2, q = t & 3;
  node = b * 64 + nl;
  if (node < N_NODES) {
    float o0 = 0.f, o1 = 0.f, o2 = 0.f, o3 = 0.f;
#pragma unroll
    for (int c4 = 0; c4 < 4; c4++) {
      float4 av = *(const float4*)(agg + nl * 16 + c4 * 4);
      float vs[4] = {av.x, av.y, av.z, av.w};
#pragma unroll
      for (int i2 = 0; i2 < 4; i2++) {
        float v = fmaxf(vs[i2], 0.f);
        const float* wr = w + (c4 * 4 + i2) * 16 + q * 4;
        o0 = fmaf(v, wr[0], o0);
        o1 = fmaf(v, wr[1], o1);
        o2 = fmaf(v, wr[2], o2);
        o3 = fmaf(v, wr[3], o3);
      }
    }
    float dn = disq[node];
    *(float4*)(ouths + (size_t)node * H + q * 4) =
        make_float4(o0 * dn, o1 * dn, o2 * dn, o3 * dn);
  }
}

// Fused gather + relu + 16x1 GEMM + disq scale -> hs3. No LDS: each lane
// holds its channel quad; dot with w3 quad, shfl reduce over 4 lanes.
__global__ void k_gath_last(const int* __restrict__ nrs, const int* __restrict__ nend,
                            const int* __restrict__ ebuf2, const float* __restrict__ disq,
                            const float* __restrict__ hs, const float* __restrict__ W3,
                            const float* __restrict__ bias, float* __restrict__ hs3) {
  int b = blockIdx.x, t = threadIdx.x;
  int grp = t >> 2, lane = t & 3;
  int node = b * 64 + grp;
  if (node >= N_NODES) return;
  const float4* hs4 = (const float4*)hs;
  int beg = nrs[node], endp = nend[node];
  float4 a = make_float4(0.f, 0.f, 0.f, 0.f);
  for (int j = beg; j < endp; j += 4) {
    int4 s = *(const int4*)(ebuf2 + j);
    float4 v0 = hs4[s.x * 4 + lane];
    float4 v1 = hs4[s.y * 4 + lane];
    float4 v2 = hs4[s.z * 4 + lane];
    float4 v3 = hs4[s.w * 4 + lane];
    a.x += (v0.x + v1.x) + (v2.x + v3.x);
    a.y += (v0.y + v1.y) + (v2.y + v3.y);
    a.z += (v0.z + v1.z) + (v2.z + v3.z);
    a.w += (v0.w + v1.w) + (v2.w + v3.w);
  }
  float dn = disq[node];
  float4 self = hs4[node * 4 + lane];
  float4 bv = *(const float4*)(bias + lane * 4);
  float4 r;
  r.x = fmaf(a.x + self.x, dn, bv.x);
  r.y = fmaf(a.y + self.y, dn, bv.y);
  r.z = fmaf(a.z + self.z, dn, bv.z);
  r.w = fmaf(a.w + self.w, dn, bv.w);
  const float4 wv = *(const float4*)(W3 + lane * 4);
  float o = fmaxf(r.x, 0.f) * wv.x;
  o = fmaf(fmaxf(r.y, 0.f), wv.y, o);
  o = fmaf(fmaxf(r.z, 0.f), wv.z, o);
  o = fmaf(fmaxf(r.w, 0.f), wv.w, o);
  o += __shfl_xor(o, 1);
  o += __shfl_xor(o, 2);
  if (lane == 0) hs3[node] = o * dn;
}

// Final 1-channel gather: 4 lanes/node, int4 index loads, shfl reduce.
__global__ void k_gath1(const int* __restrict__ nrs, const int* __restrict__ nend,
                        const int* __restrict__ ebuf2, const float* __restrict__ disq,
                        const float* __restrict__ hs3, const float* __restrict__ bias,
                        float* __restrict__ out) {
  int b = blockIdx.x, t = threadIdx.x;
  int nl = t >> 2, lane = t & 3;
  int node = b * 64 + nl;
  if (node >= N_NODES) return;
  int beg = nrs[node], endp = nend[node];
  float acc = 0.f;
  for (int j = beg + 4 * lane; j < endp; j += 16) {
    int4 s = *(const int4*)(ebuf2 + j);
    acc += (hs3[s.x] + hs3[s.y]) + (hs3[s.z] + hs3[s.w]);
  }
  acc += __shfl_xor(acc, 1);
  acc += __shfl_xor(acc, 2);
  if (lane == 0) out[node] = fmaf(acc + hs3[node], disq[node], bias[0]);
}

extern "C" void kernel_launch(void* const* d_in, const int* in_sizes, int n_in,
                              void* d_out, int out_size, void* d_ws, size_t ws_size,
                              hipStream_t stream) {
  const float* x = (const float*)d_in[0];
  const int* ei = (const int*)d_in[1];  // integer inputs delivered as int32
  const float* W1 = (const float*)d_in[2];
  const float* b1 = (const float*)d_in[3];
  const float* W2 = (const float*)d_in[4];
  const float* b2 = (const float*)d_in[5];
  const float* W3 = (const float*)d_in[6];
  const float* b3 = (const float*)d_in[7];
  float* out = (float*)d_out;

  // Workspace (~43 MB), 16B-aligned segments.
  int* ebuf = (int*)d_ws;                        // NB*CAP (14.0 MB)
  int* ebuf2 = ebuf + (size_t)NB * CAP;          // NB*CAP2 (15.2 MB), %4==0 offset
  int* gcur = ebuf2 + (size_t)NB * CAP2;         // NB
  int* nrs = gcur + NB;                          // N
  int* nend = nrs + N_NODES;                     // N
  int pad = (4 - ((NB + 2 * N_NODES) & 3)) & 3;  // realign to 16B
  float* disq = (float*)(nend + N_NODES + pad);  // N
  float* hsA = disq + N_NODES;                   // 16(N+1) (6.4 MB)
  float* hsB = hsA + (size_t)(N_NODES + 1) * H;  // 16(N+1) (6.4 MB)
  float* hs3 = hsB + (size_t)(N_NODES + 1) * H;  // N+1

  k_init<<<(NB + 63) / 64, 64, 0, stream>>>(gcur);
  k_cscatter<<<GRID_SC, TB, 0, stream>>>(ei, gcur, ebuf);
  k_bsort<<<NB, TB, 0, stream>>>(gcur, ebuf, ebuf2, nrs, nend, disq);

  // Layer 1 dense part (+ dummy rows)
  k_gemm1<<<(N_NODES + 64) / 64, 64, 0, stream>>>(x, W1, disq, hsA, hsB, hs3);
  // Layer 1 aggregation fused with layer-2 dense 16x16
  k_gath_mid<<<NBLK64, TB, 0, stream>>>(nrs, nend, ebuf2, disq, hsA, W2, b1, hsB);
  // Layer 2 aggregation fused with layer-3 dense 16x1
  k_gath_last<<<NBLK64, TB, 0, stream>>>(nrs, nend, ebuf2, disq, hsB, W3, b2, hs3);
  // Layer 3 aggregation
  k_gath1<<<NBLK64, TB, 0, stream>>>(nrs, nend, ebuf2, disq, hs3, b3, out);
}